// Round 2
// baseline (712.319 us; speedup 1.0000x reference)
//
#include <hip/hip_runtime.h>

#define N_NODES 10000
#define N_EDGES 320000
#define DIM 256
#define ED 64
#define W1_LD 576   // mlp_w1 row stride (2*HID + EDGE_DIM)

// ---------------- CSR build ----------------
__global__ void hist_kernel(const int* __restrict__ dst, int* __restrict__ cnt, int n) {
  int i = blockIdx.x * blockDim.x + threadIdx.x;
  if (i < n) atomicAdd(&cnt[dst[i]], 1);
}

// single-block exclusive scan over N counts; writes off[0..n] and cursor copy
__global__ void scan_kernel(const int* __restrict__ cnt, int* __restrict__ off,
                            int* __restrict__ cursor, int n) {
  __shared__ int sm[256];
  __shared__ int carry_s;
  if (threadIdx.x == 0) carry_s = 0;
  __syncthreads();
  for (int base = 0; base < n; base += 256) {
    int i = base + threadIdx.x;
    int v = (i < n) ? cnt[i] : 0;
    sm[threadIdx.x] = v;
    __syncthreads();
    #pragma unroll
    for (int s = 1; s < 256; s <<= 1) {
      int t = (threadIdx.x >= s) ? sm[threadIdx.x - s] : 0;
      __syncthreads();
      sm[threadIdx.x] += t;
      __syncthreads();
    }
    int excl = sm[threadIdx.x] - v + carry_s;
    if (i < n) { off[i] = excl; cursor[i] = excl; }
    __syncthreads();
    if (threadIdx.x == 0) carry_s += sm[255];
    __syncthreads();
  }
  if (threadIdx.x == 0) off[n] = carry_s;
}

__global__ void scatter_kernel(const int* __restrict__ src, const int* __restrict__ dst,
                               int* __restrict__ cursor, int* __restrict__ csr_src, int n) {
  int i = blockIdx.x * blockDim.x + threadIdx.x;
  if (i < n) {
    int p = atomicAdd(&cursor[dst[i]], 1);
    csr_src[p] = src[i];
  }
}

// ---------------- mean aggregation (CSR gather) ----------------
// 4 nodes per block (256 threads); each wave owns one node, each lane a float4
__global__ __launch_bounds__(256) void aggregate_kernel(
    const float* __restrict__ X, const int* __restrict__ off,
    const int* __restrict__ csr_src, float* __restrict__ out) {
  int node = blockIdx.x * 4 + (threadIdx.x >> 6);
  if (node >= N_NODES) return;
  int t4 = (threadIdx.x & 63) * 4;
  int beg = off[node], end = off[node + 1];
  float ax = 0.f, ay = 0.f, az = 0.f, aw = 0.f;
  int e = beg;
  for (; e + 1 < end; e += 2) {
    int s0 = csr_src[e], s1 = csr_src[e + 1];
    float4 v0 = *(const float4*)&X[(size_t)s0 * DIM + t4];
    float4 v1 = *(const float4*)&X[(size_t)s1 * DIM + t4];
    ax += v0.x + v1.x; ay += v0.y + v1.y; az += v0.z + v1.z; aw += v0.w + v1.w;
  }
  if (e < end) {
    int s0 = csr_src[e];
    float4 v0 = *(const float4*)&X[(size_t)s0 * DIM + t4];
    ax += v0.x; ay += v0.y; az += v0.z; aw += v0.w;
  }
  int deg = end - beg;
  float inv = 1.0f / (float)(deg > 0 ? deg : 1);
  float4 r; r.x = ax * inv; r.y = ay * inv; r.z = az * inv; r.w = aw * inv;
  *(float4*)&out[(size_t)node * DIM + t4] = r;
}

// ---------------- generic fp32 GEMM: C = act(A1@W1^T [+ A2@W2^T] + bias) ----------------
// A row-major [nrows][K]; W row-major [out][ldw] (dot over K); C [nrows][ldc]
// BM=128, BN=64, BK=32; 256 threads; 8x4 accum per thread
template<bool SECOND, bool RELU>
__global__ __launch_bounds__(256) void gemm_kernel(
    const float* __restrict__ A1, const float* __restrict__ W1,
    const float* __restrict__ A2, const float* __restrict__ W2,
    const float* __restrict__ bias, float* __restrict__ C,
    int nrows, int K, int ldw, int ldc) {
  __shared__ float As[32][128];
  __shared__ float Bs[32][64];
  int t = threadIdx.x;
  int tx = t & 15, ty = t >> 4;      // tx: 16 col-groups, ty: 16 row-groups
  int row0 = blockIdx.x * 128;
  int col0 = blockIdx.y * 64;

  float acc[8][4];
  #pragma unroll
  for (int i = 0; i < 8; ++i)
    #pragma unroll
    for (int j = 0; j < 4; ++j) acc[i][j] = 0.f;

  int ksteps = K / 32;
  int total = SECOND ? 2 * ksteps : ksteps;
  for (int kt = 0; kt < total; ++kt) {
    bool second = SECOND && (kt >= ksteps);
    const float* A = second ? A2 : A1;
    const float* W = second ? W2 : W1;
    int kb = (second ? (kt - ksteps) : kt) * 32;
    __syncthreads();
    // stage A tile 128x32 (coalesced loads; transposed scalar LDS writes)
    #pragma unroll
    for (int i = 0; i < 4; ++i) {
      int idx = i * 256 + t;       // 0..1023 float4 slots
      int m = idx >> 3;            // 0..127
      int kq = idx & 7;            // 0..7
      int row = row0 + m;
      float4 v = make_float4(0.f, 0.f, 0.f, 0.f);
      if (row < nrows) v = *(const float4*)&A[(size_t)row * K + kb + kq * 4];
      As[kq * 4 + 0][m] = v.x; As[kq * 4 + 1][m] = v.y;
      As[kq * 4 + 2][m] = v.z; As[kq * 4 + 3][m] = v.w;
    }
    // stage W tile 64x32
    #pragma unroll
    for (int i = 0; i < 2; ++i) {
      int idx = i * 256 + t;       // 0..511
      int o = idx >> 3;            // 0..63
      int kq = idx & 7;
      float4 v = *(const float4*)&W[(size_t)(col0 + o) * ldw + kb + kq * 4];
      Bs[kq * 4 + 0][o] = v.x; Bs[kq * 4 + 1][o] = v.y;
      Bs[kq * 4 + 2][o] = v.z; Bs[kq * 4 + 3][o] = v.w;
    }
    __syncthreads();
    #pragma unroll 8
    for (int k = 0; k < 32; ++k) {
      float4 a0 = *(const float4*)&As[k][ty * 4];
      float4 a1 = *(const float4*)&As[k][ty * 4 + 64];
      float4 b0 = *(const float4*)&Bs[k][tx * 4];
      float a[8] = {a0.x, a0.y, a0.z, a0.w, a1.x, a1.y, a1.z, a1.w};
      float b[4] = {b0.x, b0.y, b0.z, b0.w};
      #pragma unroll
      for (int i = 0; i < 8; ++i)
        #pragma unroll
        for (int j = 0; j < 4; ++j)
          acc[i][j] += a[i] * b[j];
    }
  }
  // epilogue
  float4 bv = make_float4(0.f, 0.f, 0.f, 0.f);
  if (bias) bv = *(const float4*)&bias[col0 + tx * 4];
  #pragma unroll
  for (int i = 0; i < 8; ++i) {
    int m = ty * 4 + (i & 3) + (i >> 2) * 64;
    int row = row0 + m;
    if (row < nrows) {
      float4 o4;
      o4.x = acc[i][0] + bv.x; o4.y = acc[i][1] + bv.y;
      o4.z = acc[i][2] + bv.z; o4.w = acc[i][3] + bv.w;
      if (RELU) {
        o4.x = fmaxf(o4.x, 0.f); o4.y = fmaxf(o4.y, 0.f);
        o4.z = fmaxf(o4.z, 0.f); o4.w = fmaxf(o4.w, 0.f);
      }
      *(float4*)&C[(size_t)row * ldc + col0 + tx * 4] = o4;
    }
  }
}

// ---------------- fused edge kernel ----------------
// per block: 64 edges. R = ea @ w1c^T on the fly (two 128-out halves),
// s = P[src] + Q[dst] + R (b1 folded into P), relu, dot with w2 -> logit.
#define EB 64
__global__ __launch_bounds__(256) void edge_kernel(
    const float* __restrict__ edge_attr,
    const int* __restrict__ src, const int* __restrict__ dst,
    const float* __restrict__ PQ,      // [N][512] = P | Q
    const float* __restrict__ mlp_w1,  // [256][576]
    const float* __restrict__ w2,      // [256]
    const float* __restrict__ b2,      // [1]
    float* __restrict__ out) {         // [E]
  __shared__ float w_lds[64][128];     // [k][o] current out-half of w1c
  __shared__ float ea_lds[64][EB];     // [k][edge]
  __shared__ int sid[2][EB];
  __shared__ float w2_lds[256];

  int t = threadIdx.x;
  int e0 = blockIdx.x * EB;
  w2_lds[t] = w2[t];
  if (t < EB) { sid[0][t] = src[e0 + t]; sid[1][t] = dst[e0 + t]; }
  {
    // stage edge_attr transposed: ea_lds[k][e]
    int e_l = t >> 2, q = t & 3;
    const float* ep = &edge_attr[(size_t)(e0 + e_l) * ED + q * 16];
    #pragma unroll
    for (int j = 0; j < 4; ++j) {
      float4 v = *(const float4*)&ep[j * 4];
      int k = q * 16 + j * 4;
      ea_lds[k + 0][e_l] = v.x; ea_lds[k + 1][e_l] = v.y;
      ea_lds[k + 2][e_l] = v.z; ea_lds[k + 3][e_l] = v.w;
    }
  }
  int c = t & 15, r = t >> 4;          // c: 16 out-groups, r: 16 edge-groups
  float logit[4] = {0.f, 0.f, 0.f, 0.f};

  for (int half = 0; half < 2; ++half) {
    __syncthreads();  // covers initial staging and w_lds reuse between halves
    // stage w1c half: w_lds[k][o] = mlp_w1[(half*128+o)*576 + 512 + k]
    #pragma unroll
    for (int i = 0; i < 8; ++i) {
      int idx = i * 256 + t;    // 0..2047
      int o = idx & 127;
      int kq = idx >> 7;        // 0..15
      float4 v = *(const float4*)&mlp_w1[(size_t)(half * 128 + o) * W1_LD + 512 + kq * 4];
      w_lds[kq * 4 + 0][o] = v.x; w_lds[kq * 4 + 1][o] = v.y;
      w_lds[kq * 4 + 2][o] = v.z; w_lds[kq * 4 + 3][o] = v.w;
    }
    __syncthreads();
    float acc[4][8];
    #pragma unroll
    for (int i = 0; i < 4; ++i)
      #pragma unroll
      for (int j = 0; j < 8; ++j) acc[i][j] = 0.f;
    #pragma unroll 8
    for (int k = 0; k < 64; ++k) {
      float4 a = *(const float4*)&ea_lds[k][r * 4];
      float4 w0 = *(const float4*)&w_lds[k][c * 4];
      float4 w1v = *(const float4*)&w_lds[k][c * 4 + 64];
      float av[4] = {a.x, a.y, a.z, a.w};
      float wv[8] = {w0.x, w0.y, w0.z, w0.w, w1v.x, w1v.y, w1v.z, w1v.w};
      #pragma unroll
      for (int i = 0; i < 4; ++i)
        #pragma unroll
        for (int j = 0; j < 8; ++j)
          acc[i][j] += av[i] * wv[j];
    }
    // epilogue: gather P/Q, relu, partial dot with w2
    float4 w2a = *(const float4*)&w2_lds[half * 128 + c * 4];
    float4 w2b = *(const float4*)&w2_lds[half * 128 + c * 4 + 64];
    float w2v[8] = {w2a.x, w2a.y, w2a.z, w2a.w, w2b.x, w2b.y, w2b.z, w2b.w};
    #pragma unroll
    for (int i = 0; i < 4; ++i) {
      int el = r * 4 + i;
      int sp = sid[0][el], dp = sid[1][el];
      const float* prow = &PQ[(size_t)sp * 512 + half * 128 + c * 4];
      const float* qrow = &PQ[(size_t)dp * 512 + 256 + half * 128 + c * 4];
      float4 p0 = *(const float4*)&prow[0];
      float4 p1 = *(const float4*)&prow[64];
      float4 q0 = *(const float4*)&qrow[0];
      float4 q1 = *(const float4*)&qrow[64];
      float pv[8] = {p0.x, p0.y, p0.z, p0.w, p1.x, p1.y, p1.z, p1.w};
      float qv[8] = {q0.x, q0.y, q0.z, q0.w, q1.x, q1.y, q1.z, q1.w};
      #pragma unroll
      for (int j = 0; j < 8; ++j) {
        float s = acc[i][j] + pv[j] + qv[j];
        s = fmaxf(s, 0.f);
        logit[i] += s * w2v[j];
      }
    }
  }
  // reduce over the 16 out-groups (lanes differing in low 4 bits)
  #pragma unroll
  for (int m = 1; m < 16; m <<= 1) {
    #pragma unroll
    for (int i = 0; i < 4; ++i) logit[i] += __shfl_xor(logit[i], m, 64);
  }
  if (c == 0) {
    float bb = b2[0];
    #pragma unroll
    for (int i = 0; i < 4; ++i) out[e0 + r * 4 + i] = logit[i] + bb;
  }
}

// ---------------- launch ----------------
static inline size_t alignup(size_t x) { return (x + 255) & ~(size_t)255; }

extern "C" void kernel_launch(void* const* d_in, const int* in_sizes, int n_in,
                              void* d_out, int out_size, void* d_ws, size_t ws_size,
                              hipStream_t stream) {
  const float* x    = (const float*)d_in[0];
  const float* ea   = (const float*)d_in[1];
  const float* c1wl = (const float*)d_in[2];
  const float* c1bl = (const float*)d_in[3];
  const float* c1wr = (const float*)d_in[4];
  const float* c2wl = (const float*)d_in[5];
  const float* c2bl = (const float*)d_in[6];
  const float* c2wr = (const float*)d_in[7];
  const float* w1   = (const float*)d_in[8];
  const float* b1   = (const float*)d_in[9];
  const float* w2   = (const float*)d_in[10];
  const float* b2   = (const float*)d_in[11];
  const int*   ei   = (const int*)d_in[12];
  const int* src = ei;
  const int* dst = ei + N_EDGES;
  float* out = (float*)d_out;

  // workspace carve-up (~53 MB)
  char* p = (char*)d_ws;
  size_t o = 0;
  int* cnt      = (int*)(p + o); o += alignup(N_NODES * 4);
  int* off      = (int*)(p + o); o += alignup((N_NODES + 1) * 4);
  int* cursor   = (int*)(p + o); o += alignup(N_NODES * 4);
  int* csr_src  = (int*)(p + o); o += alignup(N_EDGES * 4);
  float* mbuf   = (float*)(p + o); o += alignup((size_t)N_NODES * DIM * 4);
  float* h1     = (float*)(p + o); o += alignup((size_t)N_NODES * DIM * 4);
  float* h2     = (float*)(p + o); o += alignup((size_t)N_NODES * DIM * 4);
  float* PQ     = (float*)(p + o); o += alignup((size_t)N_NODES * 512 * 4);

  hipMemsetAsync(cnt, 0, N_NODES * 4, stream);
  hist_kernel<<<(N_EDGES + 255) / 256, 256, 0, stream>>>(dst, cnt, N_EDGES);
  scan_kernel<<<1, 256, 0, stream>>>(cnt, off, cursor, N_NODES);
  scatter_kernel<<<(N_EDGES + 255) / 256, 256, 0, stream>>>(src, dst, cursor, csr_src, N_EDGES);

  dim3 ggrid((N_NODES + 127) / 128, 4);

  // conv1: h1 = relu(mean(x) @ c1wl^T + c1bl + x @ c1wr^T)
  aggregate_kernel<<<(N_NODES + 3) / 4, 256, 0, stream>>>(x, off, csr_src, mbuf);
  gemm_kernel<true, true><<<ggrid, 256, 0, stream>>>(
      mbuf, c1wl, x, c1wr, c1bl, h1, N_NODES, DIM, DIM, DIM);

  // conv2: h2 = mean(h1) @ c2wl^T + c2bl + h1 @ c2wr^T
  aggregate_kernel<<<(N_NODES + 3) / 4, 256, 0, stream>>>(h1, off, csr_src, mbuf);
  gemm_kernel<true, false><<<ggrid, 256, 0, stream>>>(
      mbuf, c2wl, h1, c2wr, c2bl, h2, N_NODES, DIM, DIM, DIM);

  // P = h2 @ w1a^T + b1 (cols 0..255 of PQ), Q = h2 @ w1b^T (cols 256..511)
  gemm_kernel<false, false><<<ggrid, 256, 0, stream>>>(
      h2, w1, h2, w1, b1, PQ, N_NODES, DIM, W1_LD, 512);
  gemm_kernel<false, false><<<ggrid, 256, 0, stream>>>(
      h2, w1 + 256, h2, w1 + 256, nullptr, PQ + 256, N_NODES, DIM, W1_LD, 512);

  // fused edge MLP
  edge_kernel<<<N_EDGES / EB, 256, 0, stream>>>(ea, src, dst, PQ, w1, w2, b2, out);
}

// Round 3
// 663.851 us; speedup vs baseline: 1.0730x; 1.0730x over previous
//
#include <hip/hip_runtime.h>

#define N_NODES 10000
#define N_EDGES 320000
#define DIM 256
#define ED 64
#define W1_LD 576   // mlp_w1 row stride (2*HID + EDGE_DIM)

// ---------------- CSR build ----------------
__global__ void hist_kernel(const int* __restrict__ dst, int* __restrict__ cnt, int n) {
  int i = blockIdx.x * blockDim.x + threadIdx.x;
  if (i < n) atomicAdd(&cnt[dst[i]], 1);
}

// single-block scan, wave-shuffle based (3 barriers per 256-chunk)
__global__ void scan_kernel(const int* __restrict__ cnt, int* __restrict__ off,
                            int* __restrict__ cursor, int n) {
  __shared__ int wsum[4];
  __shared__ int carry_s;
  int t = threadIdx.x, lane = t & 63, w = t >> 6;
  if (t == 0) carry_s = 0;
  __syncthreads();
  for (int base = 0; base < n; base += 256) {
    int i = base + t;
    int v = (i < n) ? cnt[i] : 0;
    int sc = v;  // inclusive wave scan
    #pragma unroll
    for (int s = 1; s < 64; s <<= 1) {
      int u = __shfl_up(sc, s, 64);
      if (lane >= s) sc += u;
    }
    if (lane == 63) wsum[w] = sc;
    __syncthreads();
    int woff = 0, tot = 0;
    #pragma unroll
    for (int j = 0; j < 4; ++j) { int s = wsum[j]; if (j < w) woff += s; tot += s; }
    int excl = sc - v + woff + carry_s;
    if (i < n) { off[i] = excl; cursor[i] = excl; }
    __syncthreads();
    if (t == 0) carry_s += tot;
    __syncthreads();
  }
  if (t == 0) off[n] = carry_s;
}

__global__ void scatter_kernel(const int* __restrict__ src, const int* __restrict__ dst,
                               int* __restrict__ cursor, int* __restrict__ csr_src, int n) {
  int i = blockIdx.x * blockDim.x + threadIdx.x;
  if (i < n) {
    int p = atomicAdd(&cursor[dst[i]], 1);
    csr_src[p] = src[i];
  }
}

// ---------------- mean aggregation (CSR gather) ----------------
// 4 nodes/block; each wave owns one node, each lane a float4; 4 rows in flight
__global__ __launch_bounds__(256) void aggregate_kernel(
    const float* __restrict__ X, const int* __restrict__ off,
    const int* __restrict__ csr_src, float* __restrict__ out) {
  int node = blockIdx.x * 4 + (threadIdx.x >> 6);
  int t4 = (threadIdx.x & 63) * 4;
  int beg = off[node], end = off[node + 1];
  float x0=0.f,y0=0.f,z0=0.f,w0=0.f, x1=0.f,y1=0.f,z1=0.f,w1=0.f;
  float x2=0.f,y2=0.f,z2=0.f,w2=0.f, x3=0.f,y3=0.f,z3=0.f,w3=0.f;
  int e = beg;
  for (; e + 3 < end; e += 4) {
    int s0 = csr_src[e], s1 = csr_src[e+1], s2 = csr_src[e+2], s3 = csr_src[e+3];
    float4 v0 = *(const float4*)&X[(size_t)s0 * DIM + t4];
    float4 v1 = *(const float4*)&X[(size_t)s1 * DIM + t4];
    float4 v2 = *(const float4*)&X[(size_t)s2 * DIM + t4];
    float4 v3 = *(const float4*)&X[(size_t)s3 * DIM + t4];
    x0+=v0.x; y0+=v0.y; z0+=v0.z; w0+=v0.w;
    x1+=v1.x; y1+=v1.y; z1+=v1.z; w1+=v1.w;
    x2+=v2.x; y2+=v2.y; z2+=v2.z; w2+=v2.w;
    x3+=v3.x; y3+=v3.y; z3+=v3.z; w3+=v3.w;
  }
  for (; e < end; ++e) {
    int s = csr_src[e];
    float4 v = *(const float4*)&X[(size_t)s * DIM + t4];
    x0+=v.x; y0+=v.y; z0+=v.z; w0+=v.w;
  }
  int deg = end - beg;
  float inv = 1.0f / (float)(deg > 0 ? deg : 1);
  float4 r;
  r.x = (x0+x1+x2+x3) * inv; r.y = (y0+y1+y2+y3) * inv;
  r.z = (z0+z1+z2+z3) * inv; r.w = (w0+w1+w2+w3) * inv;
  *(float4*)&out[(size_t)node * DIM + t4] = r;
}

// ---------------- generic fp32 GEMM: C = act(A1@W1^T [+ A2@W2^T] + bias) ----------------
// A row-major [nrows][K]; W row-major [out][ldw] (dot over K); C [nrows][ldc]
// BM=128, BN=64, BK=32; 256 threads; 8x4 accum per thread.
// wsplit: col blocks with col0 >= wsplit use W shifted to the (k+wsplit) column
// region with row index rebased (merged P|Q GEMM); bias applies only col0<wsplit.
template<bool SECOND, bool RELU>
__global__ __launch_bounds__(256) void gemm_kernel(
    const float* __restrict__ W1_, const float* __restrict__ A1,
    const float* __restrict__ A2, const float* __restrict__ W2_,
    const float* __restrict__ bias, float* __restrict__ C,
    int nrows, int K, int ldw, int ldc, int wsplit) {
  __shared__ float As[32][128];
  __shared__ float Bs[32][64];
  int t = threadIdx.x;
  int tx = t & 15, ty = t >> 4;
  int row0 = blockIdx.x * 128;
  int col0 = blockIdx.y * 64;

  const float* W1 = W1_;
  const float* W2 = W2_;
  bool qreg = (col0 >= wsplit);
  if (qreg) {
    ptrdiff_t adj = (ptrdiff_t)wsplit - (ptrdiff_t)wsplit * (ptrdiff_t)ldw;
    W1 = W1_ + adj; W2 = W2_ + adj;
  }

  float acc[8][4];
  #pragma unroll
  for (int i = 0; i < 8; ++i)
    #pragma unroll
    for (int j = 0; j < 4; ++j) acc[i][j] = 0.f;

  int ksteps = K / 32;
  int total = SECOND ? 2 * ksteps : ksteps;
  for (int kt = 0; kt < total; ++kt) {
    bool second = SECOND && (kt >= ksteps);
    const float* A = second ? A2 : A1;
    const float* W = second ? W2 : W1;
    int kb = (second ? (kt - ksteps) : kt) * 32;
    __syncthreads();
    #pragma unroll
    for (int i = 0; i < 4; ++i) {
      int idx = i * 256 + t;
      int m = idx >> 3;
      int kq = idx & 7;
      int row = row0 + m;
      float4 v = make_float4(0.f, 0.f, 0.f, 0.f);
      if (row < nrows) v = *(const float4*)&A[(size_t)row * K + kb + kq * 4];
      As[kq * 4 + 0][m] = v.x; As[kq * 4 + 1][m] = v.y;
      As[kq * 4 + 2][m] = v.z; As[kq * 4 + 3][m] = v.w;
    }
    #pragma unroll
    for (int i = 0; i < 2; ++i) {
      int idx = i * 256 + t;
      int o = idx >> 3;
      int kq = idx & 7;
      float4 v = *(const float4*)&W[(size_t)(col0 + o) * ldw + kb + kq * 4];
      Bs[kq * 4 + 0][o] = v.x; Bs[kq * 4 + 1][o] = v.y;
      Bs[kq * 4 + 2][o] = v.z; Bs[kq * 4 + 3][o] = v.w;
    }
    __syncthreads();
    #pragma unroll 8
    for (int k = 0; k < 32; ++k) {
      float4 a0 = *(const float4*)&As[k][ty * 4];
      float4 a1 = *(const float4*)&As[k][ty * 4 + 64];
      float4 b0 = *(const float4*)&Bs[k][tx * 4];
      float a[8] = {a0.x, a0.y, a0.z, a0.w, a1.x, a1.y, a1.z, a1.w};
      float b[4] = {b0.x, b0.y, b0.z, b0.w};
      #pragma unroll
      for (int i = 0; i < 8; ++i)
        #pragma unroll
        for (int j = 0; j < 4; ++j)
          acc[i][j] += a[i] * b[j];
    }
  }
  float4 bv = make_float4(0.f, 0.f, 0.f, 0.f);
  if (bias && !qreg) bv = *(const float4*)&bias[col0 + tx * 4];
  #pragma unroll
  for (int i = 0; i < 8; ++i) {
    int m = ty * 4 + (i & 3) + (i >> 2) * 64;
    int row = row0 + m;
    if (row < nrows) {
      float4 o4;
      o4.x = acc[i][0] + bv.x; o4.y = acc[i][1] + bv.y;
      o4.z = acc[i][2] + bv.z; o4.w = acc[i][3] + bv.w;
      if (RELU) {
        o4.x = fmaxf(o4.x, 0.f); o4.y = fmaxf(o4.y, 0.f);
        o4.z = fmaxf(o4.z, 0.f); o4.w = fmaxf(o4.w, 0.f);
      }
      *(float4*)&C[(size_t)row * ldc + col0 + tx * 4] = o4;
    }
  }
}

// ---------------- fused edge kernel ----------------
// per block: 64 edges. R = ea @ w1c^T (two 128-out halves), with P/Q gathers
// issued BEFORE the FMA loop (T14 async split) so L2/L3 latency hides.
#define EB 64
__global__ __launch_bounds__(256) void edge_kernel(
    const float* __restrict__ edge_attr,
    const int* __restrict__ src, const int* __restrict__ dst,
    const float* __restrict__ PQ,      // [N][512] = P(+b1) | Q
    const float* __restrict__ mlp_w1,  // [256][576]
    const float* __restrict__ w2,      // [256]
    const float* __restrict__ b2,      // [1]
    float* __restrict__ out) {         // [E]
  __shared__ float w_lds[64][128];     // [k][o] current out-half of w1c
  __shared__ float ea_lds[64][EB];     // [k][edge]
  __shared__ int sid[2][EB];

  int t = threadIdx.x;
  int e0 = blockIdx.x * EB;
  if (t < EB) { sid[0][t] = src[e0 + t]; sid[1][t] = dst[e0 + t]; }
  {
    int e_l = t >> 2, q = t & 3;
    const float* ep = &edge_attr[(size_t)(e0 + e_l) * ED + q * 16];
    #pragma unroll
    for (int j = 0; j < 4; ++j) {
      float4 v = *(const float4*)&ep[j * 4];
      int k = q * 16 + j * 4;
      ea_lds[k + 0][e_l] = v.x; ea_lds[k + 1][e_l] = v.y;
      ea_lds[k + 2][e_l] = v.z; ea_lds[k + 3][e_l] = v.w;
    }
  }
  int c = t & 15, r = t >> 4;
  float logit[4] = {0.f, 0.f, 0.f, 0.f};
  __syncthreads();   // sid + ea_lds visible

  const float* pbase[4];
  const float* qbase[4];
  #pragma unroll
  for (int i = 0; i < 4; ++i) {
    int el = r * 4 + i;
    pbase[i] = &PQ[(size_t)sid[0][el] * 512 + c * 4];
    qbase[i] = &PQ[(size_t)sid[1][el] * 512 + 256 + c * 4];
  }

  float4 pf[4][2], qf[4][2];
  // prefetch half 0 gathers (in flight across w-staging + FMA loop)
  #pragma unroll
  for (int i = 0; i < 4; ++i) {
    pf[i][0] = *(const float4*)&pbase[i][0];
    pf[i][1] = *(const float4*)&pbase[i][64];
    qf[i][0] = *(const float4*)&qbase[i][0];
    qf[i][1] = *(const float4*)&qbase[i][64];
  }

  for (int half = 0; half < 2; ++half) {
    // stage w1c half: w_lds[k][o] = mlp_w1[(half*128+o)*576 + 512 + k]
    #pragma unroll
    for (int i = 0; i < 8; ++i) {
      int idx = i * 256 + t;
      int o = idx & 127;
      int kq = idx >> 7;
      float4 v = *(const float4*)&mlp_w1[(size_t)(half * 128 + o) * W1_LD + 512 + kq * 4];
      w_lds[kq * 4 + 0][o] = v.x; w_lds[kq * 4 + 1][o] = v.y;
      w_lds[kq * 4 + 2][o] = v.z; w_lds[kq * 4 + 3][o] = v.w;
    }
    __syncthreads();
    float acc[4][8];
    #pragma unroll
    for (int i = 0; i < 4; ++i)
      #pragma unroll
      for (int j = 0; j < 8; ++j) acc[i][j] = 0.f;
    #pragma unroll 8
    for (int k = 0; k < 64; ++k) {
      float4 a = *(const float4*)&ea_lds[k][r * 4];
      float4 wv0 = *(const float4*)&w_lds[k][c * 4];
      float4 wv1 = *(const float4*)&w_lds[k][c * 4 + 64];
      float av[4] = {a.x, a.y, a.z, a.w};
      float wv[8] = {wv0.x, wv0.y, wv0.z, wv0.w, wv1.x, wv1.y, wv1.z, wv1.w};
      #pragma unroll
      for (int i = 0; i < 4; ++i)
        #pragma unroll
        for (int j = 0; j < 8; ++j)
          acc[i][j] += av[i] * wv[j];
    }
    // epilogue: consume prefetched P/Q, relu, partial dot with w2
    float4 w2a = *(const float4*)&w2[half * 128 + c * 4];
    float4 w2b = *(const float4*)&w2[half * 128 + c * 4 + 64];
    float w2v[8] = {w2a.x, w2a.y, w2a.z, w2a.w, w2b.x, w2b.y, w2b.z, w2b.w};
    #pragma unroll
    for (int i = 0; i < 4; ++i) {
      float pv[8] = {pf[i][0].x, pf[i][0].y, pf[i][0].z, pf[i][0].w,
                     pf[i][1].x, pf[i][1].y, pf[i][1].z, pf[i][1].w};
      float qv[8] = {qf[i][0].x, qf[i][0].y, qf[i][0].z, qf[i][0].w,
                     qf[i][1].x, qf[i][1].y, qf[i][1].z, qf[i][1].w};
      #pragma unroll
      for (int j = 0; j < 8; ++j) {
        float s = acc[i][j] + pv[j] + qv[j];
        s = fmaxf(s, 0.f);
        logit[i] += s * w2v[j];
      }
    }
    if (half == 0) {
      // prefetch half-1 gathers now that the registers are free; latency
      // hides under the half-1 w-staging + FMA loop
      #pragma unroll
      for (int i = 0; i < 4; ++i) {
        pf[i][0] = *(const float4*)&pbase[i][128];
        pf[i][1] = *(const float4*)&pbase[i][192];
        qf[i][0] = *(const float4*)&qbase[i][128];
        qf[i][1] = *(const float4*)&qbase[i][192];
      }
      __syncthreads();  // all waves done reading w_lds before restage
    }
  }
  #pragma unroll
  for (int m = 1; m < 16; m <<= 1) {
    #pragma unroll
    for (int i = 0; i < 4; ++i) logit[i] += __shfl_xor(logit[i], m, 64);
  }
  if (c == 0) {
    float bb = b2[0];
    #pragma unroll
    for (int i = 0; i < 4; ++i) out[e0 + r * 4 + i] = logit[i] + bb;
  }
}

// ---------------- launch ----------------
static inline size_t alignup(size_t x) { return (x + 255) & ~(size_t)255; }

extern "C" void kernel_launch(void* const* d_in, const int* in_sizes, int n_in,
                              void* d_out, int out_size, void* d_ws, size_t ws_size,
                              hipStream_t stream) {
  const float* x    = (const float*)d_in[0];
  const float* ea   = (const float*)d_in[1];
  const float* c1wl = (const float*)d_in[2];
  const float* c1bl = (const float*)d_in[3];
  const float* c1wr = (const float*)d_in[4];
  const float* c2wl = (const float*)d_in[5];
  const float* c2bl = (const float*)d_in[6];
  const float* c2wr = (const float*)d_in[7];
  const float* w1   = (const float*)d_in[8];
  const float* b1   = (const float*)d_in[9];
  const float* w2   = (const float*)d_in[10];
  const float* b2   = (const float*)d_in[11];
  const int*   ei   = (const int*)d_in[12];
  const int* src = ei;
  const int* dst = ei + N_EDGES;
  float* out = (float*)d_out;

  char* p = (char*)d_ws;
  size_t o = 0;
  int* cnt      = (int*)(p + o); o += alignup(N_NODES * 4);
  int* off      = (int*)(p + o); o += alignup((N_NODES + 1) * 4);
  int* cursor   = (int*)(p + o); o += alignup(N_NODES * 4);
  int* csr_src  = (int*)(p + o); o += alignup(N_EDGES * 4);
  float* mbuf   = (float*)(p + o); o += alignup((size_t)N_NODES * DIM * 4);
  float* h1     = (float*)(p + o); o += alignup((size_t)N_NODES * DIM * 4);
  float* h2     = (float*)(p + o); o += alignup((size_t)N_NODES * DIM * 4);
  float* PQ     = (float*)(p + o); o += alignup((size_t)N_NODES * 512 * 4);

  hipMemsetAsync(cnt, 0, N_NODES * 4, stream);
  hist_kernel<<<(N_EDGES + 255) / 256, 256, 0, stream>>>(dst, cnt, N_EDGES);
  scan_kernel<<<1, 256, 0, stream>>>(cnt, off, cursor, N_NODES);
  scatter_kernel<<<(N_EDGES + 255) / 256, 256, 0, stream>>>(src, dst, cursor, csr_src, N_EDGES);

  dim3 ggrid((N_NODES + 127) / 128, 4);
  dim3 pqgrid((N_NODES + 127) / 128, 8);
  const int NOSPLIT = 1 << 30;

  // conv1: h1 = relu(mean(x) @ c1wl^T + c1bl + x @ c1wr^T)
  aggregate_kernel<<<N_NODES / 4, 256, 0, stream>>>(x, off, csr_src, mbuf);
  gemm_kernel<true, true><<<ggrid, 256, 0, stream>>>(
      c1wl, mbuf, x, c1wr, c1bl, h1, N_NODES, DIM, DIM, DIM, NOSPLIT);

  // conv2: h2 = mean(h1) @ c2wl^T + c2bl + h1 @ c2wr^T
  aggregate_kernel<<<N_NODES / 4, 256, 0, stream>>>(h1, off, csr_src, mbuf);
  gemm_kernel<true, false><<<ggrid, 256, 0, stream>>>(
      c2wl, mbuf, h1, c2wr, c2bl, h2, N_NODES, DIM, DIM, DIM, NOSPLIT);

  // merged P|Q: PQ[:,0:256] = h2 @ w1[:,0:256]^T + b1 ; PQ[:,256:512] = h2 @ w1[:,256:512]^T
  gemm_kernel<false, false><<<pqgrid, 256, 0, stream>>>(
      w1, h2, h2, w1, b1, PQ, N_NODES, DIM, W1_LD, 512, 256);

  // fused edge MLP
  edge_kernel<<<N_EDGES / EB, 256, 0, stream>>>(ea, src, dst, PQ, w1, w2, b2, out);
}

// Round 4
// 616.381 us; speedup vs baseline: 1.1556x; 1.0770x over previous
//
#include <hip/hip_runtime.h>

#define N_NODES 10000
#define N_EDGES 320000
#define DIM 256
#define ED 64
#define W1_LD 576   // mlp_w1 row stride (2*HID + EDGE_DIM)

// ---------------- CSR build ----------------
__global__ void hist_kernel(const int* __restrict__ dst, int* __restrict__ cnt, int n) {
  int i = blockIdx.x * blockDim.x + threadIdx.x;
  if (i < n) atomicAdd(&cnt[dst[i]], 1);
}

// single-block scan, wave-shuffle based
__global__ void scan_kernel(const int* __restrict__ cnt, int* __restrict__ off,
                            int* __restrict__ cursor, int n) {
  __shared__ int wsum[4];
  __shared__ int carry_s;
  int t = threadIdx.x, lane = t & 63, w = t >> 6;
  if (t == 0) carry_s = 0;
  __syncthreads();
  for (int base = 0; base < n; base += 256) {
    int i = base + t;
    int v = (i < n) ? cnt[i] : 0;
    int sc = v;  // inclusive wave scan
    #pragma unroll
    for (int s = 1; s < 64; s <<= 1) {
      int u = __shfl_up(sc, s, 64);
      if (lane >= s) sc += u;
    }
    if (lane == 63) wsum[w] = sc;
    __syncthreads();
    int woff = 0, tot = 0;
    #pragma unroll
    for (int j = 0; j < 4; ++j) { int s = wsum[j]; if (j < w) woff += s; tot += s; }
    int excl = sc - v + woff + carry_s;
    if (i < n) { off[i] = excl; cursor[i] = excl; }
    __syncthreads();
    if (t == 0) carry_s += tot;
    __syncthreads();
  }
  if (t == 0) off[n] = carry_s;
}

__global__ void scatter_kernel(const int* __restrict__ src, const int* __restrict__ dst,
                               int* __restrict__ cursor, int* __restrict__ csr_src,
                               int* __restrict__ csr_dst, int* __restrict__ csr_eid, int n) {
  int i = blockIdx.x * blockDim.x + threadIdx.x;
  if (i < n) {
    int d = dst[i];
    int p = atomicAdd(&cursor[d], 1);
    csr_src[p] = src[i];
    csr_dst[p] = d;
    csr_eid[p] = i;
  }
}

// ---------------- mean aggregation (CSR gather) ----------------
// 4 nodes/block; each wave owns one node, each lane a float4; 4 rows in flight
__global__ __launch_bounds__(256) void aggregate_kernel(
    const float* __restrict__ X, const int* __restrict__ off,
    const int* __restrict__ csr_src, float* __restrict__ out) {
  int node = blockIdx.x * 4 + (threadIdx.x >> 6);
  int t4 = (threadIdx.x & 63) * 4;
  int beg = off[node], end = off[node + 1];
  float x0=0.f,y0=0.f,z0=0.f,w0=0.f, x1=0.f,y1=0.f,z1=0.f,w1=0.f;
  float x2=0.f,y2=0.f,z2=0.f,w2=0.f, x3=0.f,y3=0.f,z3=0.f,w3=0.f;
  int e = beg;
  for (; e + 3 < end; e += 4) {
    int s0 = csr_src[e], s1 = csr_src[e+1], s2 = csr_src[e+2], s3 = csr_src[e+3];
    float4 v0 = *(const float4*)&X[(size_t)s0 * DIM + t4];
    float4 v1 = *(const float4*)&X[(size_t)s1 * DIM + t4];
    float4 v2 = *(const float4*)&X[(size_t)s2 * DIM + t4];
    float4 v3 = *(const float4*)&X[(size_t)s3 * DIM + t4];
    x0+=v0.x; y0+=v0.y; z0+=v0.z; w0+=v0.w;
    x1+=v1.x; y1+=v1.y; z1+=v1.z; w1+=v1.w;
    x2+=v2.x; y2+=v2.y; z2+=v2.z; w2+=v2.w;
    x3+=v3.x; y3+=v3.y; z3+=v3.z; w3+=v3.w;
  }
  for (; e < end; ++e) {
    int s = csr_src[e];
    float4 v = *(const float4*)&X[(size_t)s * DIM + t4];
    x0+=v.x; y0+=v.y; z0+=v.z; w0+=v.w;
  }
  int deg = end - beg;
  float inv = 1.0f / (float)(deg > 0 ? deg : 1);
  float4 r;
  r.x = (x0+x1+x2+x3) * inv; r.y = (y0+y1+y2+y3) * inv;
  r.z = (z0+z1+z2+z3) * inv; r.w = (w0+w1+w2+w3) * inv;
  *(float4*)&out[(size_t)node * DIM + t4] = r;
}

// ---------------- generic fp32 GEMM: C = act(A1@W1^T [+ A2@W2^T] + bias) ----------------
// A row-major [nrows][K]; W row-major [out][ldw] (dot over K); C [nrows][ldc]
// BM=64, BN=64, BK=32; 256 threads; 4x4 accum per thread.
// wsplit: col blocks with col0 >= wsplit use W rebased (merged P|Q GEMM);
// bias applies only to col0 < wsplit.
template<bool SECOND, bool RELU>
__global__ __launch_bounds__(256) void gemm_kernel(
    const float* __restrict__ W1_, const float* __restrict__ A1,
    const float* __restrict__ A2, const float* __restrict__ W2_,
    const float* __restrict__ bias, float* __restrict__ C,
    int nrows, int K, int ldw, int ldc, int wsplit) {
  __shared__ float As[32][64];
  __shared__ float Bs[32][64];
  int t = threadIdx.x;
  int tx = t & 15, ty = t >> 4;
  int row0 = blockIdx.x * 64;
  int col0 = blockIdx.y * 64;

  const float* W1 = W1_;
  const float* W2 = W2_;
  bool qreg = (col0 >= wsplit);
  if (qreg) {
    ptrdiff_t adj = (ptrdiff_t)wsplit - (ptrdiff_t)wsplit * (ptrdiff_t)ldw;
    W1 = W1_ + adj; W2 = W2_ + adj;
  }

  float acc[4][4];
  #pragma unroll
  for (int i = 0; i < 4; ++i)
    #pragma unroll
    for (int j = 0; j < 4; ++j) acc[i][j] = 0.f;

  int ksteps = K / 32;
  int total = SECOND ? 2 * ksteps : ksteps;
  for (int kt = 0; kt < total; ++kt) {
    bool second = SECOND && (kt >= ksteps);
    const float* A = second ? A2 : A1;
    const float* W = second ? W2 : W1;
    int kb = (second ? (kt - ksteps) : kt) * 32;
    __syncthreads();
    // stage A tile 64x32
    #pragma unroll
    for (int i = 0; i < 2; ++i) {
      int idx = i * 256 + t;       // 0..511 float4 slots
      int m = idx >> 3;            // 0..63
      int kq = idx & 7;            // 0..7
      int row = row0 + m;
      float4 v = make_float4(0.f, 0.f, 0.f, 0.f);
      if (row < nrows) v = *(const float4*)&A[(size_t)row * K + kb + kq * 4];
      As[kq * 4 + 0][m] = v.x; As[kq * 4 + 1][m] = v.y;
      As[kq * 4 + 2][m] = v.z; As[kq * 4 + 3][m] = v.w;
    }
    // stage W tile 64x32
    #pragma unroll
    for (int i = 0; i < 2; ++i) {
      int idx = i * 256 + t;
      int o = idx >> 3;
      int kq = idx & 7;
      float4 v = *(const float4*)&W[(size_t)(col0 + o) * ldw + kb + kq * 4];
      Bs[kq * 4 + 0][o] = v.x; Bs[kq * 4 + 1][o] = v.y;
      Bs[kq * 4 + 2][o] = v.z; Bs[kq * 4 + 3][o] = v.w;
    }
    __syncthreads();
    #pragma unroll 8
    for (int k = 0; k < 32; ++k) {
      float4 a0 = *(const float4*)&As[k][ty * 4];
      float4 b0 = *(const float4*)&Bs[k][tx * 4];
      float a[4] = {a0.x, a0.y, a0.z, a0.w};
      float b[4] = {b0.x, b0.y, b0.z, b0.w};
      #pragma unroll
      for (int i = 0; i < 4; ++i)
        #pragma unroll
        for (int j = 0; j < 4; ++j)
          acc[i][j] += a[i] * b[j];
    }
  }
  float4 bv = make_float4(0.f, 0.f, 0.f, 0.f);
  if (bias && !qreg) bv = *(const float4*)&bias[col0 + tx * 4];
  #pragma unroll
  for (int i = 0; i < 4; ++i) {
    int row = row0 + ty * 4 + i;
    if (row < nrows) {
      float4 o4;
      o4.x = acc[i][0] + bv.x; o4.y = acc[i][1] + bv.y;
      o4.z = acc[i][2] + bv.z; o4.w = acc[i][3] + bv.w;
      if (RELU) {
        o4.x = fmaxf(o4.x, 0.f); o4.y = fmaxf(o4.y, 0.f);
        o4.z = fmaxf(o4.z, 0.f); o4.w = fmaxf(o4.w, 0.f);
      }
      *(float4*)&C[(size_t)row * ldc + col0 + tx * 4] = o4;
    }
  }
}

// ---------------- fused edge kernel (CSR-ordered) ----------------
// per block: 64 CSR-consecutive edges (dst-sorted -> Q gather is cache-hot).
// R = ea @ w1c^T in four 64-out chunks (w_lds[64][64] = 16 KB), P/Q gathers
// prefetched one chunk ahead. LDS 32.2 KB + launch_bounds(256,4) -> 4 blocks/CU.
#define EB 64
__global__ __launch_bounds__(256, 4) void edge_kernel(
    const float* __restrict__ edge_attr,
    const int* __restrict__ csr_src, const int* __restrict__ csr_dst,
    const int* __restrict__ csr_eid,
    const float* __restrict__ PQ,      // [N][512] = P(+b1) | Q
    const float* __restrict__ mlp_w1,  // [256][576]
    const float* __restrict__ w2,      // [256]
    const float* __restrict__ b2,      // [1]
    float* __restrict__ out) {         // [E]
  __shared__ float w_lds[64][64];      // [k][o] current 64-out chunk of w1c
  __shared__ float ea_lds[64][EB];     // [k][edge]

  int t = threadIdx.x;
  int e0 = blockIdx.x * EB;
  // stage edge_attr transposed via eid indirection
  {
    int e_l = t >> 2, q = t & 3;
    int eid = csr_eid[e0 + e_l];
    const float* ep = &edge_attr[(size_t)eid * ED + q * 16];
    #pragma unroll
    for (int j = 0; j < 4; ++j) {
      float4 v = *(const float4*)&ep[j * 4];
      int k = q * 16 + j * 4;
      ea_lds[k + 0][e_l] = v.x; ea_lds[k + 1][e_l] = v.y;
      ea_lds[k + 2][e_l] = v.z; ea_lds[k + 3][e_l] = v.w;
    }
  }
  int c = t & 15, r = t >> 4;
  const float* pbase[4];
  const float* qbase[4];
  int eout[4];
  #pragma unroll
  for (int i = 0; i < 4; ++i) {
    int el = e0 + r * 4 + i;
    pbase[i] = &PQ[(size_t)csr_src[el] * 512 + c * 4];
    qbase[i] = &PQ[(size_t)csr_dst[el] * 512 + 256 + c * 4];
    eout[i] = csr_eid[el];
  }
  float logit[4] = {0.f, 0.f, 0.f, 0.f};
  float4 pf[4], qf[4];
  #pragma unroll
  for (int i = 0; i < 4; ++i) {
    pf[i] = *(const float4*)&pbase[i][0];
    qf[i] = *(const float4*)&qbase[i][0];
  }

  for (int chunk = 0; chunk < 4; ++chunk) {
    // stage w chunk: w_lds[k][o] = mlp_w1[(chunk*64+o)*576 + 512 + k]
    #pragma unroll
    for (int i = 0; i < 4; ++i) {
      int idx = i * 256 + t;       // 0..1023
      int o = idx & 63;
      int kq = idx >> 6;           // 0..15
      float4 v = *(const float4*)&mlp_w1[(size_t)(chunk * 64 + o) * W1_LD + 512 + kq * 4];
      w_lds[kq * 4 + 0][o] = v.x; w_lds[kq * 4 + 1][o] = v.y;
      w_lds[kq * 4 + 2][o] = v.z; w_lds[kq * 4 + 3][o] = v.w;
    }
    __syncthreads();               // w (and chunk0: ea) visible
    float acc[4][4];
    #pragma unroll
    for (int i = 0; i < 4; ++i)
      #pragma unroll
      for (int j = 0; j < 4; ++j) acc[i][j] = 0.f;
    #pragma unroll 8
    for (int k = 0; k < 64; ++k) {
      float4 a = *(const float4*)&ea_lds[k][r * 4];
      float4 wv4 = *(const float4*)&w_lds[k][c * 4];
      float av[4] = {a.x, a.y, a.z, a.w};
      float wv[4] = {wv4.x, wv4.y, wv4.z, wv4.w};
      #pragma unroll
      for (int i = 0; i < 4; ++i)
        #pragma unroll
        for (int j = 0; j < 4; ++j)
          acc[i][j] += av[i] * wv[j];
    }
    // epilogue: consume prefetched P/Q, relu, partial dot with w2
    float4 w2v = *(const float4*)&w2[chunk * 64 + c * 4];
    #pragma unroll
    for (int i = 0; i < 4; ++i) {
      float s0 = fmaxf(acc[i][0] + pf[i].x + qf[i].x, 0.f);
      float s1 = fmaxf(acc[i][1] + pf[i].y + qf[i].y, 0.f);
      float s2 = fmaxf(acc[i][2] + pf[i].z + qf[i].z, 0.f);
      float s3 = fmaxf(acc[i][3] + pf[i].w + qf[i].w, 0.f);
      logit[i] += s0 * w2v.x + s1 * w2v.y + s2 * w2v.z + s3 * w2v.w;
    }
    if (chunk < 3) {
      int coff = (chunk + 1) * 64;
      #pragma unroll
      for (int i = 0; i < 4; ++i) {
        pf[i] = *(const float4*)&pbase[i][coff];
        qf[i] = *(const float4*)&qbase[i][coff];
      }
      __syncthreads();             // all waves done reading w_lds before restage
    }
  }
  // reduce over the 16 out-groups (lanes differing in low 4 bits)
  #pragma unroll
  for (int m = 1; m < 16; m <<= 1) {
    #pragma unroll
    for (int i = 0; i < 4; ++i) logit[i] += __shfl_xor(logit[i], m, 64);
  }
  if (c == 0) {
    float bb = b2[0];
    #pragma unroll
    for (int i = 0; i < 4; ++i) out[eout[i]] = logit[i] + bb;
  }
}

// ---------------- launch ----------------
static inline size_t alignup(size_t x) { return (x + 255) & ~(size_t)255; }

extern "C" void kernel_launch(void* const* d_in, const int* in_sizes, int n_in,
                              void* d_out, int out_size, void* d_ws, size_t ws_size,
                              hipStream_t stream) {
  const float* x    = (const float*)d_in[0];
  const float* ea   = (const float*)d_in[1];
  const float* c1wl = (const float*)d_in[2];
  const float* c1bl = (const float*)d_in[3];
  const float* c1wr = (const float*)d_in[4];
  const float* c2wl = (const float*)d_in[5];
  const float* c2bl = (const float*)d_in[6];
  const float* c2wr = (const float*)d_in[7];
  const float* w1   = (const float*)d_in[8];
  const float* b1   = (const float*)d_in[9];
  const float* w2   = (const float*)d_in[10];
  const float* b2   = (const float*)d_in[11];
  const int*   ei   = (const int*)d_in[12];
  const int* src = ei;
  const int* dst = ei + N_EDGES;
  float* out = (float*)d_out;

  char* p = (char*)d_ws;
  size_t o = 0;
  int* cnt      = (int*)(p + o); o += alignup(N_NODES * 4);
  int* off      = (int*)(p + o); o += alignup((N_NODES + 1) * 4);
  int* cursor   = (int*)(p + o); o += alignup(N_NODES * 4);
  int* csr_src  = (int*)(p + o); o += alignup(N_EDGES * 4);
  int* csr_dst  = (int*)(p + o); o += alignup(N_EDGES * 4);
  int* csr_eid  = (int*)(p + o); o += alignup(N_EDGES * 4);
  float* mbuf   = (float*)(p + o); o += alignup((size_t)N_NODES * DIM * 4);
  float* h1     = (float*)(p + o); o += alignup((size_t)N_NODES * DIM * 4);
  float* h2     = (float*)(p + o); o += alignup((size_t)N_NODES * DIM * 4);
  float* PQ     = (float*)(p + o); o += alignup((size_t)N_NODES * 512 * 4);

  hipMemsetAsync(cnt, 0, N_NODES * 4, stream);
  hist_kernel<<<(N_EDGES + 255) / 256, 256, 0, stream>>>(dst, cnt, N_EDGES);
  scan_kernel<<<1, 256, 0, stream>>>(cnt, off, cursor, N_NODES);
  scatter_kernel<<<(N_EDGES + 255) / 256, 256, 0, stream>>>(
      src, dst, cursor, csr_src, csr_dst, csr_eid, N_EDGES);

  dim3 ggrid((N_NODES + 63) / 64, 4);
  dim3 pqgrid((N_NODES + 63) / 64, 8);
  const int NOSPLIT = 1 << 30;

  // conv1: h1 = relu(mean(x) @ c1wl^T + c1bl + x @ c1wr^T)
  aggregate_kernel<<<N_NODES / 4, 256, 0, stream>>>(x, off, csr_src, mbuf);
  gemm_kernel<true, true><<<ggrid, 256, 0, stream>>>(
      c1wl, mbuf, x, c1wr, c1bl, h1, N_NODES, DIM, DIM, DIM, NOSPLIT);

  // conv2: h2 = mean(h1) @ c2wl^T + c2bl + h1 @ c2wr^T
  aggregate_kernel<<<N_NODES / 4, 256, 0, stream>>>(h1, off, csr_src, mbuf);
  gemm_kernel<true, false><<<ggrid, 256, 0, stream>>>(
      c2wl, mbuf, h1, c2wr, c2bl, h2, N_NODES, DIM, DIM, DIM, NOSPLIT);

  // merged P|Q: PQ[:,0:256] = h2 @ w1[:,0:256]^T + b1 ; PQ[:,256:512] = h2 @ w1[:,256:512]^T
  gemm_kernel<false, false><<<pqgrid, 256, 0, stream>>>(
      w1, h2, h2, w1, b1, PQ, N_NODES, DIM, W1_LD, 512, 256);

  // fused edge MLP over CSR-ordered edges
  edge_kernel<<<N_EDGES / EB, 256, 0, stream>>>(
      ea, csr_src, csr_dst, csr_eid, PQ, w1, w2, b2, out);
}